// Round 1
// baseline (135.666 us; speedup 1.0000x reference)
//
#include <hip/hip_runtime.h>
#include <hip/hip_cooperative_groups.h>
#include <stdint.h>

namespace cg = cooperative_groups;

#define HW 4194304      // 2048*2048
#define WIDTH 2048
#define F(x) ((float)(x))   // double literal -> f32, exactly like numpy scalar promotion

// ---------------------------------------------------------------------------
// Bit-exact replication of glibc sysdeps/ieee754/flt-32/s_cbrtf.c (pre-2.41)
// — what np.cbrt(float32) resolves to on the host. EMPIRICAL RULE (R2/R5/R6
// vs R3): ALL THREE channels (fx, fy, fz) must use this exact path; any
// deviation in fx/fz fails at absmax 2.73e-2 even though the perturbation
// model says it shouldn't. Do not substitute HW transcendentals here.
// ---------------------------------------------------------------------------
__device__ __forceinline__ float cbrtf_glibc(float x) {
    unsigned int bits = __float_as_uint(x);
    int xe = (int)((bits >> 23) & 0xFF) - 126;
    float xm = __uint_as_float((bits & 0x007FFFFFu) | 0x3F000000u);

    static const double factor[5] = {
        1.0 / 1.5874010519681994748,   // 1 / 2^(2/3)
        1.0 / 1.2599210498948731648,   // 1 / 2^(1/3)
        1.0,
        1.2599210498948731648,         // 2^(1/3)
        1.5874010519681994748          // 2^(2/3)
    };

    double xmd = (double)xm;
    double p = __dsub_rn(0.697570460207922770, __dmul_rn(0.191502161678719066, xmd));
    p = __dadd_rn(0.492659620528969547, __dmul_rn(p, xmd));
    float u = (float)p;

    float t2 = __fmul_rn(__fmul_rn(u, u), u);   // float, two roundings (as glibc)

    double ud  = (double)u;
    double t2d = (double)t2;
    double num = __dmul_rn(ud, __dadd_rn(t2d, __dmul_rn(2.0, xmd)));
    double den = __dadd_rn(__dmul_rn(2.0, t2d), xmd);
    double ym  = __dmul_rn(__ddiv_rn(num, den), factor[2 + (xe % 3)]);
    float ymf = (float)ym;

    return ldexpf(ymf, xe / 3);
}

// Exact forward path — the ONLY forward path (see empirical rule above).
__device__ __forceinline__ void rgb2lab_px(float r, float g, float b,
                                           int& l8, float& A_, float& B_) {
    float X = __fadd_rn(__fadd_rn(__fmul_rn(r, F(0.412453)), __fmul_rn(g, F(0.357580))), __fmul_rn(b, F(0.180423)));
    float Y = __fadd_rn(__fadd_rn(__fmul_rn(r, F(0.212671)), __fmul_rn(g, F(0.715160))), __fmul_rn(b, F(0.072169)));
    float Z = __fadd_rn(__fadd_rn(__fmul_rn(r, F(0.019334)), __fmul_rn(g, F(0.119193))), __fmul_rn(b, F(0.950227)));
    X = __fdiv_rn(X, F(0.950456));
    Z = __fdiv_rn(Z, F(1.088754));
    const float EPS = F(0.008856);
    const float C0  = F(16.0 / 116.0);
    float fx = (X > EPS) ? cbrtf_glibc(X) : __fadd_rn(__fmul_rn(F(7.787), X), C0);
    float fy = (Y > EPS) ? cbrtf_glibc(Y) : __fadd_rn(__fmul_rn(F(7.787), Y), C0);
    float fz = (Z > EPS) ? cbrtf_glibc(Z) : __fadd_rn(__fmul_rn(F(7.787), Z), C0);
    float L  = __fsub_rn(__fmul_rn(F(116.0), fy), F(16.0));
    A_ = __fmul_rn(F(500.0), __fsub_rn(fx, fy));
    B_ = __fmul_rn(F(200.0), __fsub_rn(fy, fz));
    float Lr = rintf(__fmul_rn(L, F(255.0 / 100.0)));
    Lr = fminf(fmaxf(Lr, 0.0f), 255.0f);
    l8 = (int)Lr;
}

// lab2rgb epilogue shared by fused + fallback apply.
__device__ __forceinline__ void lab2rgb_store(float Leq, float A_, float B_,
                                              float* __restrict__ out, int idx) {
    const float EPS = F(0.008856);
    const float C0  = F(16.0 / 116.0);
    float fy2 = __fdiv_rn(__fadd_rn(Leq, 16.0f), 116.0f);
    float fx2 = __fadd_rn(fy2, __fdiv_rn(A_, 500.0f));
    float fz2 = __fsub_rn(fy2, __fdiv_rn(B_, 200.0f));
    float t3;
    t3 = fx2 * fx2 * fx2;
    float X = ((t3 > EPS) ? t3 : __fdiv_rn(__fsub_rn(fx2, C0), F(7.787))) * F(0.950456);
    t3 = fy2 * fy2 * fy2;
    float Y = ((t3 > EPS) ? t3 : __fdiv_rn(__fsub_rn(fy2, C0), F(7.787))) * F(1.0);
    t3 = fz2 * fz2 * fz2;
    float Z = ((t3 > EPS) ? t3 : __fdiv_rn(__fsub_rn(fz2, C0), F(7.787))) * F(1.088754);
    float rr = __fadd_rn(__fadd_rn(__fmul_rn(X, F(3.240479)),  __fmul_rn(Y, F(-1.537150))), __fmul_rn(Z, F(-0.498535)));
    float gg = __fadd_rn(__fadd_rn(__fmul_rn(X, F(-0.969256)), __fmul_rn(Y, F(1.875992))),  __fmul_rn(Z, F(0.041556)));
    float bb = __fadd_rn(__fadd_rn(__fmul_rn(X, F(0.055648)),  __fmul_rn(Y, F(-0.204043))), __fmul_rn(Z, F(1.057311)));
    rr = fminf(fmaxf(rr, 0.0f), 1.0f);
    gg = fminf(fmaxf(gg, 0.0f), 1.0f);
    bb = fminf(fmaxf(bb, 0.0f), 1.0f);
    out[idx]          = rr;
    out[idx + HW]     = gg;
    out[idx + 2 * HW] = bb;
}

// ===========================================================================
// FUSED cooperative kernel: 1024 blocks x 256 threads, 4 blocks/CU on 256 CUs.
// Block b owns rows {2b, 2b+1} (always the same tile-row AND the same
// (y0,y1) interp pair: floor boundaries sit at y=127.5+256k, i.e. always
// between an odd row and the next even row). Lab values (A,B,l8) for the
// block's 16 px/thread live in REGISTERS across both grid syncs — the 75 MB
// ab/l8 workspace round-trip of the 3-kernel pipeline is gone.
// ===========================================================================
__global__ __launch_bounds__(256, 4) void k_fused(
        const float* __restrict__ x,
        unsigned int* __restrict__ hist,
        float* __restrict__ lut,
        float* __restrict__ out) {
    __shared__ float lds[4096];    // phase1: 2048 u32 hist | phase2: 512 f32 | phase3: 16KB lutS
    const int t = threadIdx.x;
    const int b = blockIdx.x;
    const int r0 = b * 2;

    // ------------------- phase 1: rgb2lab + per-block histogram -------------
    unsigned int* h = (unsigned int*)lds;
    #pragma unroll
    for (int i = 0; i < 8; ++i) h[i * 256 + t] = 0;
    __syncthreads();

    const float* R  = x;
    const float* G  = x + HW;
    const float* Bp = x + 2 * HW;

    float Areg[2][8], Breg[2][8];
    unsigned int l8p[2][2] = {{0u, 0u}, {0u, 0u}};   // 8 x u8 per row, packed

    #pragma unroll
    for (int rr = 0; rr < 2; ++rr) {
        const int rowbase = (r0 + rr) * WIDTH;
        #pragma unroll
        for (int c = 0; c < 8; ++c) {
            int col = c * 256 + t;
            int idx = rowbase + col;
            float r = R[idx], g = G[idx], bb = Bp[idx];
            int l8; float A_, B_;
            rgb2lab_px(r, g, bb, l8, A_, B_);
            Areg[rr][c] = A_;
            Breg[rr][c] = B_;
            l8p[rr][c >> 2] |= (unsigned int)l8 << ((c & 3) * 8);
            atomicAdd(&h[((col >> 8) << 8) + l8], 1u);
        }
    }
    __syncthreads();
    {
        const int tilerow = r0 >> 8;
        unsigned int* gh = hist + tilerow * 2048;
        #pragma unroll
        for (int i = 0; i < 8; ++i) {
            unsigned int v = h[i * 256 + t];
            if (v) atomicAdd(&gh[i * 256 + t], v);
        }
    }
    __threadfence();
    cg::this_grid().sync();

    // ------------------- phase 2: LUT for 64 tiles (blocks 0..63) -----------
    // All sums are multiples of 2^-8 bounded by 2^16 (integer counts; excess
    // integer; excess/256 pow2-scaled) => exactly representable in f32 in ANY
    // association => bit-identical to the serial reference cumsum.
    if (b < 64) {
        float hval = (float)hist[b * 256 + t];
        float* sh = lds;
        sh[t] = fmaxf(hval - 2560.0f, 0.0f);   // clip = 10*65536/256 = 2560 exactly
        __syncthreads();
        for (int s = 128; s > 0; s >>= 1) {
            if (t < s) sh[t] += sh[t + s];
            __syncthreads();
        }
        float excess = sh[0];
        float val = __fadd_rn(fminf(hval, 2560.0f), __fmul_rn(excess, F(1.0 / 256.0)));
        float* sc = lds + 256;
        sc[t] = val;
        __syncthreads();
        #pragma unroll
        for (int s = 1; s < 256; s <<= 1) {   // Hillis-Steele inclusive scan
            float add = (t >= s) ? sc[t - s] : 0.0f;
            __syncthreads();
            val = __fadd_rn(val, add);
            sc[t] = val;
            __syncthreads();
        }
        float lv = rintf(__fmul_rn(val, F(255.0 / 65536.0)));
        lut[b * 256 + t] = fminf(fmaxf(lv, 0.0f), 255.0f);
    }
    cg::this_grid().sync();

    // ------------------- phase 3: stage 2 LUT tile-rows, interp, lab2rgb ----
    float fyc = fminf(fmaxf(((float)r0 + 0.5f) * (1.0f / 256.0f) - 0.5f, 0.0f), 7.0f);
    int y0 = (int)floorf(fyc);
    int y1 = min(y0 + 1, 7);
    const float* ltop = lut + y0 * 2048;
    const float* lbot = lut + y1 * 2048;
    #pragma unroll
    for (int i = 0; i < 8; ++i) {
        lds[i * 256 + t]        = ltop[i * 256 + t];
        lds[2048 + i * 256 + t] = lbot[i * 256 + t];
    }
    __syncthreads();

    #pragma unroll
    for (int rr = 0; rr < 2; ++rr) {
        const int y = r0 + rr;
        float fyr = fminf(fmaxf(((float)y + 0.5f) * (1.0f / 256.0f) - 0.5f, 0.0f), 7.0f);
        float wy = __fsub_rn(fyr, (float)y0);     // y0 identical for both rows
        float omwy = __fsub_rn(1.0f, wy);
        const int rowbase = y * WIDTH;
        #pragma unroll
        for (int c = 0; c < 8; ++c) {
            int col = c * 256 + t;
            int idx = rowbase + col;
            int l8 = (int)((l8p[rr][c >> 2] >> ((c & 3) * 8)) & 0xFFu);
            float A_ = Areg[rr][c];
            float B_ = Breg[rr][c];
            float fxc = fminf(fmaxf(((float)col + 0.5f) * (1.0f / 256.0f) - 0.5f, 0.0f), 7.0f);
            int x0 = (int)floorf(fxc);
            int x1 = min(x0 + 1, 7);
            float wx = __fsub_rn(fxc, (float)x0);
            float omwx = __fsub_rn(1.0f, wx);
            float g00 = lds[x0 * 256 + l8];
            float g01 = lds[x1 * 256 + l8];
            float g10 = lds[2048 + x0 * 256 + l8];
            float g11 = lds[2048 + x1 * 256 + l8];
            float top = __fadd_rn(__fmul_rn(omwx, g00), __fmul_rn(wx, g01));
            float bot = __fadd_rn(__fmul_rn(omwx, g10), __fmul_rn(wx, g11));
            float Leq = __fmul_rn(__fadd_rn(__fmul_rn(omwy, top), __fmul_rn(wy, bot)),
                                  F(100.0 / 255.0));
            lab2rgb_store(Leq, A_, B_, out, idx);
        }
    }
}

// ===========================================================================
// FALLBACK: the previous verified 3-kernel pipeline (used only if the
// cooperative launch cannot be used on this runtime/harness).
// ===========================================================================
__global__ __launch_bounds__(256) void k_hist(const float* __restrict__ x,
        unsigned int* __restrict__ hist,
        float2* __restrict__ ab_out,
        unsigned char* __restrict__ l8_out, int store) {
    __shared__ unsigned int h[2048];
    const int t = threadIdx.x;
    const int y = blockIdx.x;
    #pragma unroll
    for (int i = 0; i < 8; ++i) h[i * 256 + t] = 0;
    __syncthreads();
    const float* R  = x;
    const float* G  = x + HW;
    const float* Bp = x + 2 * HW;
    const int rowbase = y * WIDTH;
    #pragma unroll
    for (int c = 0; c < 8; ++c) {
        int col = c * 256 + t;
        int idx = rowbase + col;
        float r = R[idx], g = G[idx], b = Bp[idx];
        int l8; float A_, B_;
        rgb2lab_px(r, g, b, l8, A_, B_);
        if (store) {
            ab_out[idx] = make_float2(A_, B_);
            l8_out[idx] = (unsigned char)l8;
        }
        atomicAdd(&h[((col >> 8) << 8) + l8], 1u);
    }
    __syncthreads();
    const int tilerow = y >> 8;
    unsigned int* gh = hist + tilerow * 2048;
    #pragma unroll
    for (int i = 0; i < 8; ++i) {
        unsigned int v = h[i * 256 + t];
        if (v) atomicAdd(&gh[i * 256 + t], v);
    }
}

__global__ __launch_bounds__(256) void k_lut(const unsigned int* __restrict__ hist,
                                             float* __restrict__ lut) {
    __shared__ float sh[256];
    __shared__ float hc[256];
    const int t = threadIdx.x;
    const int tile = blockIdx.x;
    float h = (float)hist[tile * 256 + t];
    sh[t] = fmaxf(h - 2560.0f, 0.0f);
    __syncthreads();
    for (int s = 128; s > 0; s >>= 1) {
        if (t < s) sh[t] += sh[t + s];
        __syncthreads();
    }
    float excess = sh[0];
    hc[t] = __fadd_rn(fminf(h, 2560.0f), __fmul_rn(excess, F(1.0 / 256.0)));
    __syncthreads();
    if (t == 0) {
        float c = 0.0f;
        for (int i = 0; i < 256; ++i) { c = __fadd_rn(c, hc[i]); hc[i] = c; }
    }
    __syncthreads();
    float v = rintf(__fmul_rn(hc[t], F(255.0 / 65536.0)));
    lut[tile * 256 + t] = fminf(fmaxf(v, 0.0f), 255.0f);
}

__global__ __launch_bounds__(256) void k_apply(const float* __restrict__ x,
        const float* __restrict__ lut,
        const float2* __restrict__ ab_in,
        const unsigned char* __restrict__ l8_in,
        float* __restrict__ out, int stored) {
    __shared__ float lutS[4096];
    const int t = threadIdx.x;
    const int y = blockIdx.x;

    float fyc = fminf(fmaxf(((float)y + 0.5f) * (1.0f / 256.0f) - 0.5f, 0.0f), 7.0f);
    int y0 = (int)floorf(fyc); int y1 = min(y0 + 1, 7);
    float wy = __fsub_rn(fyc, (float)y0);
    float omwy = __fsub_rn(1.0f, wy);

    const float* ltop = lut + y0 * 2048;
    const float* lbot = lut + y1 * 2048;
    #pragma unroll
    for (int i = 0; i < 8; ++i) {
        lutS[i * 256 + t]        = ltop[i * 256 + t];
        lutS[2048 + i * 256 + t] = lbot[i * 256 + t];
    }
    __syncthreads();

    const int rowbase = y * WIDTH;
    #pragma unroll
    for (int c = 0; c < 8; ++c) {
        int col = c * 256 + t;
        int idx = rowbase + col;
        int l8; float A_, B_;
        if (stored) {
            float2 ab = ab_in[idx];
            A_ = ab.x; B_ = ab.y;
            l8 = (int)l8_in[idx];
        } else {
            float r = x[idx], g = x[idx + HW], b = x[idx + 2 * HW];
            rgb2lab_px(r, g, b, l8, A_, B_);
        }
        float fxc = fminf(fmaxf(((float)col + 0.5f) * (1.0f / 256.0f) - 0.5f, 0.0f), 7.0f);
        int x0 = (int)floorf(fxc); int x1 = min(x0 + 1, 7);
        float wx = __fsub_rn(fxc, (float)x0);
        float omwx = __fsub_rn(1.0f, wx);
        float g00 = lutS[x0 * 256 + l8];
        float g01 = lutS[x1 * 256 + l8];
        float g10 = lutS[2048 + x0 * 256 + l8];
        float g11 = lutS[2048 + x1 * 256 + l8];
        float top = __fadd_rn(__fmul_rn(omwx, g00), __fmul_rn(wx, g01));
        float bot = __fadd_rn(__fmul_rn(omwx, g10), __fmul_rn(wx, g11));
        float Leq = __fmul_rn(__fadd_rn(__fmul_rn(omwy, top), __fmul_rn(wy, bot)),
                              F(100.0 / 255.0));
        lab2rgb_store(Leq, A_, B_, out, idx);
    }
}

extern "C" void kernel_launch(void* const* d_in, const int* in_sizes, int n_in,
                              void* d_out, int out_size, void* d_ws, size_t ws_size,
                              hipStream_t stream) {
    const float* x = (const float*)d_in[0];
    float* out = (float*)d_out;
    char* ws = (char*)d_ws;
    unsigned int* hist = (unsigned int*)ws;            // 64*256*4 = 64 KiB
    float* lut = (float*)(ws + 65536);                 // 64*256*4 = 64 KiB

    // One-time host-side occupancy check: cooperative launch of 1024 blocks
    // needs 4 co-resident blocks/CU on 256 CUs.
    static int coop_state = -1;
    if (coop_state < 0) {
        int nb = 0, ncu = 0, dev = 0;
        (void)hipGetDevice(&dev);
        hipError_t e1 = hipOccupancyMaxActiveBlocksPerMultiprocessor(&nb, k_fused, 256, 0);
        hipError_t e2 = hipDeviceGetAttribute(&ncu, hipDeviceAttributeMultiprocessorCount, dev);
        coop_state = (e1 == hipSuccess && e2 == hipSuccess && nb * ncu >= 1024) ? 1 : 0;
    }

    (void)hipMemsetAsync(hist, 0, 65536, stream);

    bool done = false;
    if (coop_state == 1) {
        const float* xa = x; unsigned int* ha = hist; float* la = lut; float* oa = out;
        void* kargs[] = { (void*)&xa, (void*)&ha, (void*)&la, (void*)&oa };
        hipError_t le = hipLaunchCooperativeKernel((const void*)k_fused,
                                                   dim3(1024), dim3(256),
                                                   kargs, 0u, stream);
        done = (le == hipSuccess);
        if (!done) coop_state = 0;   // don't retry on later calls
    }

    if (!done) {
        const size_t off = 131072;
        float2* ab_buf = (float2*)(ws + off);                               // 32 MiB
        unsigned char* l8_buf = (unsigned char*)(ws + off + (size_t)HW * 8); // 4 MiB
        const size_t need = off + (size_t)HW * 9;
        const int store = (ws_size >= need) ? 1 : 0;
        k_hist<<<2048, 256, 0, stream>>>(x, hist, ab_buf, l8_buf, store);
        k_lut<<<64, 256, 0, stream>>>(hist, lut);
        k_apply<<<2048, 256, 0, stream>>>(x, lut, ab_buf, l8_buf, out, store);
    }
}

// Round 2
// 134.107 us; speedup vs baseline: 1.0116x; 1.0116x over previous
//
#include <hip/hip_runtime.h>
#include <stdint.h>

#define HW 4194304      // 2048*2048
#define WIDTH 2048
#define NBLK 2048       // fused grid: one block per image row, all co-resident
#define F(x) ((float)(x))   // double literal -> f32, exactly like numpy scalar promotion

// ---------------------------------------------------------------------------
// Bit-exact replication of glibc sysdeps/ieee754/flt-32/s_cbrtf.c (pre-2.41)
// — what np.cbrt(float32) resolves to on the host. EMPIRICAL RULE (R2/R5/R6
// vs R3): ALL THREE channels (fx, fy, fz) must use this exact path; any
// deviation in fx/fz fails at absmax 2.73e-2 even though the perturbation
// model says it shouldn't. Do not substitute HW transcendentals here.
// ---------------------------------------------------------------------------
__device__ __forceinline__ float cbrtf_glibc(float x) {
    unsigned int bits = __float_as_uint(x);
    int xe = (int)((bits >> 23) & 0xFF) - 126;
    float xm = __uint_as_float((bits & 0x007FFFFFu) | 0x3F000000u);

    static const double factor[5] = {
        1.0 / 1.5874010519681994748,   // 1 / 2^(2/3)
        1.0 / 1.2599210498948731648,   // 1 / 2^(1/3)
        1.0,
        1.2599210498948731648,         // 2^(1/3)
        1.5874010519681994748          // 2^(2/3)
    };

    double xmd = (double)xm;
    double p = __dsub_rn(0.697570460207922770, __dmul_rn(0.191502161678719066, xmd));
    p = __dadd_rn(0.492659620528969547, __dmul_rn(p, xmd));
    float u = (float)p;

    float t2 = __fmul_rn(__fmul_rn(u, u), u);   // float, two roundings (as glibc)

    double ud  = (double)u;
    double t2d = (double)t2;
    double num = __dmul_rn(ud, __dadd_rn(t2d, __dmul_rn(2.0, xmd)));
    double den = __dadd_rn(__dmul_rn(2.0, t2d), xmd);
    double ym  = __dmul_rn(__ddiv_rn(num, den), factor[2 + (xe % 3)]);
    float ymf = (float)ym;

    return ldexpf(ymf, xe / 3);
}

// Exact forward path — the ONLY forward path (see empirical rule above).
__device__ __forceinline__ void rgb2lab_px(float r, float g, float b,
                                           int& l8, float& A_, float& B_) {
    float X = __fadd_rn(__fadd_rn(__fmul_rn(r, F(0.412453)), __fmul_rn(g, F(0.357580))), __fmul_rn(b, F(0.180423)));
    float Y = __fadd_rn(__fadd_rn(__fmul_rn(r, F(0.212671)), __fmul_rn(g, F(0.715160))), __fmul_rn(b, F(0.072169)));
    float Z = __fadd_rn(__fadd_rn(__fmul_rn(r, F(0.019334)), __fmul_rn(g, F(0.119193))), __fmul_rn(b, F(0.950227)));
    X = __fdiv_rn(X, F(0.950456));
    Z = __fdiv_rn(Z, F(1.088754));
    const float EPS = F(0.008856);
    const float C0  = F(16.0 / 116.0);
    float fx = (X > EPS) ? cbrtf_glibc(X) : __fadd_rn(__fmul_rn(F(7.787), X), C0);
    float fy = (Y > EPS) ? cbrtf_glibc(Y) : __fadd_rn(__fmul_rn(F(7.787), Y), C0);
    float fz = (Z > EPS) ? cbrtf_glibc(Z) : __fadd_rn(__fmul_rn(F(7.787), Z), C0);
    float L  = __fsub_rn(__fmul_rn(F(116.0), fy), F(16.0));
    A_ = __fmul_rn(F(500.0), __fsub_rn(fx, fy));
    B_ = __fmul_rn(F(200.0), __fsub_rn(fy, fz));
    float Lr = rintf(__fmul_rn(L, F(255.0 / 100.0)));
    Lr = fminf(fmaxf(Lr, 0.0f), 255.0f);
    l8 = (int)Lr;
}

// lab2rgb epilogue shared by fused + fallback apply.
__device__ __forceinline__ void lab2rgb_store(float Leq, float A_, float B_,
                                              float* __restrict__ out, int idx) {
    const float EPS = F(0.008856);
    const float C0  = F(16.0 / 116.0);
    float fy2 = __fdiv_rn(__fadd_rn(Leq, 16.0f), 116.0f);
    float fx2 = __fadd_rn(fy2, __fdiv_rn(A_, 500.0f));
    float fz2 = __fsub_rn(fy2, __fdiv_rn(B_, 200.0f));
    float t3;
    t3 = fx2 * fx2 * fx2;
    float X = ((t3 > EPS) ? t3 : __fdiv_rn(__fsub_rn(fx2, C0), F(7.787))) * F(0.950456);
    t3 = fy2 * fy2 * fy2;
    float Y = ((t3 > EPS) ? t3 : __fdiv_rn(__fsub_rn(fy2, C0), F(7.787))) * F(1.0);
    t3 = fz2 * fz2 * fz2;
    float Z = ((t3 > EPS) ? t3 : __fdiv_rn(__fsub_rn(fz2, C0), F(7.787))) * F(1.088754);
    float rr = __fadd_rn(__fadd_rn(__fmul_rn(X, F(3.240479)),  __fmul_rn(Y, F(-1.537150))), __fmul_rn(Z, F(-0.498535)));
    float gg = __fadd_rn(__fadd_rn(__fmul_rn(X, F(-0.969256)), __fmul_rn(Y, F(1.875992))),  __fmul_rn(Z, F(0.041556)));
    float bb = __fadd_rn(__fadd_rn(__fmul_rn(X, F(0.055648)),  __fmul_rn(Y, F(-0.204043))), __fmul_rn(Z, F(1.057311)));
    rr = fminf(fmaxf(rr, 0.0f), 1.0f);
    gg = fminf(fmaxf(gg, 0.0f), 1.0f);
    bb = fminf(fmaxf(bb, 0.0f), 1.0f);
    out[idx]          = rr;
    out[idx + HW]     = gg;
    out[idx + 2 * HW] = bb;
}

// ===========================================================================
// FUSED single kernel, REGULAR launch (graph-capturable). 2048 blocks x 256
// threads, __launch_bounds__(256,8) forces <=64 VGPR -> 8 blocks/CU -> all
// 2048 blocks co-resident on 256 CUs (pre-verified on host via occupancy
// query; fallback pipeline otherwise). One hand-rolled device-scope grid
// barrier after histogram accumulation. Each block then REDUNDANTLY computes
// the LUTs of the 2 tile-rows it needs via an exact wave-level scan (all
// partial sums are multiples of 2^-8 bounded by 2^24 => exact in f32 in ANY
// association => bit-identical to the serial reference cumsum) — this removes
// the second barrier, the k_lut latency bubble, and the global lut buffer.
// A,B,l8 for the block's 8 px/thread stay in registers across the barrier =>
// the 75 MB ab/l8 HBM round-trip of the 3-kernel pipeline is gone.
// ===========================================================================
__global__ __launch_bounds__(256, 8) void k_fused_row(
        const float* __restrict__ x,
        unsigned int* __restrict__ hist,
        unsigned int* __restrict__ bar,
        float* __restrict__ out) {
    __shared__ float lutS[4096];   // 16 KB; first 8 KB doubles as u32 hist in phase 1
    unsigned int* h = (unsigned int*)lutS;
    const int t = threadIdx.x;
    const int y = blockIdx.x;

    // ------------------- phase 1: rgb2lab + row histogram -> global hist ----
    #pragma unroll
    for (int i = 0; i < 8; ++i) h[i * 256 + t] = 0;
    __syncthreads();

    float A[8], B[8];
    unsigned int l8p[2] = {0u, 0u};          // 8 x u8 packed
    const int rowbase = y * WIDTH;
    #pragma unroll
    for (int c = 0; c < 8; ++c) {
        int col = c * 256 + t;
        int idx = rowbase + col;
        float r = x[idx], g = x[idx + HW], b = x[idx + 2 * HW];
        int l8;
        rgb2lab_px(r, g, b, l8, A[c], B[c]);
        l8p[c >> 2] |= (unsigned int)l8 << ((c & 3) * 8);
        atomicAdd(&h[((col >> 8) << 8) + l8], 1u);
    }
    __syncthreads();
    {
        unsigned int* gh = hist + (y >> 8) * 2048;
        #pragma unroll
        for (int i = 0; i < 8; ++i) {
            unsigned int v = h[i * 256 + t];
            if (v) atomicAdd(&gh[i * 256 + t], v);
        }
    }

    // ------------------- grid barrier (device scope, bounded spin) ----------
    __syncthreads();
    if (t == 0) {
        __threadfence();   // release: make this block's hist atomics visible
        unsigned int arrived = __hip_atomic_fetch_add(&bar[0], 1u,
                                   __ATOMIC_ACQ_REL, __HIP_MEMORY_SCOPE_AGENT);
        if (arrived == NBLK - 1) {
            __hip_atomic_store(&bar[1], 1u, __ATOMIC_RELEASE, __HIP_MEMORY_SCOPE_AGENT);
        } else {
            // bounded spin: can never hang the harness; occupancy is
            // pre-verified on host so the bound is unreachable in practice.
            for (long it = 0; it < (1L << 26); ++it) {
                if (__hip_atomic_load(&bar[1], __ATOMIC_ACQUIRE,
                                      __HIP_MEMORY_SCOPE_AGENT) != 0u) break;
                __builtin_amdgcn_s_sleep(2);
            }
        }
    }
    __syncthreads();

    // ------------------- phase 2: per-block LUTs for tile-rows y0,y1 --------
    float fyc = fminf(fmaxf(((float)y + 0.5f) * (1.0f / 256.0f) - 0.5f, 0.0f), 7.0f);
    int y0 = (int)floorf(fyc);
    int y1 = min(y0 + 1, 7);
    float wy = __fsub_rn(fyc, (float)y0);
    float omwy = __fsub_rn(1.0f, wy);

    {
        const int lane = t & 63;
        const int w = t >> 6;                 // 4 waves, 4 tiles each
        #pragma unroll
        for (int i = 0; i < 4; ++i) {
            int gidx = w * 4 + i;             // 0..15
            int trow = gidx >> 3;             // 0 = top (y0), 1 = bottom (y1)
            int tcol = gidx & 7;
            int tile = (trow ? y1 : y0) * 8 + tcol;
            const unsigned int* hp = hist + tile * 256 + lane * 4;
            // agent-scope atomic loads: dodge any stale per-XCD cache line
            float h0 = (float)__hip_atomic_load(&hp[0], __ATOMIC_RELAXED, __HIP_MEMORY_SCOPE_AGENT);
            float h1 = (float)__hip_atomic_load(&hp[1], __ATOMIC_RELAXED, __HIP_MEMORY_SCOPE_AGENT);
            float h2 = (float)__hip_atomic_load(&hp[2], __ATOMIC_RELAXED, __HIP_MEMORY_SCOPE_AGENT);
            float h3 = (float)__hip_atomic_load(&hp[3], __ATOMIC_RELAXED, __HIP_MEMORY_SCOPE_AGENT);
            // clip excess (integers, exact in any association)
            float e = __fadd_rn(__fadd_rn(fmaxf(h0 - 2560.0f, 0.0f),
                                          fmaxf(h1 - 2560.0f, 0.0f)),
                                __fadd_rn(fmaxf(h2 - 2560.0f, 0.0f),
                                          fmaxf(h3 - 2560.0f, 0.0f)));
            #pragma unroll
            for (int d = 1; d < 64; d <<= 1) e = __fadd_rn(e, __shfl_xor(e, d));
            float ex = __fmul_rn(e, F(1.0 / 256.0));   // pow2 scale, exact
            float v0 = __fadd_rn(fminf(h0, 2560.0f), ex);
            float v1 = __fadd_rn(fminf(h1, 2560.0f), ex);
            float v2 = __fadd_rn(fminf(h2, 2560.0f), ex);
            float v3 = __fadd_rn(fminf(h3, 2560.0f), ex);
            // lane-local inclusive prefix (exact)
            float s0 = v0;
            float s1 = __fadd_rn(s0, v1);
            float s2 = __fadd_rn(s1, v2);
            float s3 = __fadd_rn(s2, v3);
            // wave inclusive scan of per-lane totals (exact)
            float sc = s3;
            #pragma unroll
            for (int d = 1; d < 64; d <<= 1) {
                float u2 = __shfl_up(sc, d);
                if (lane >= d) sc = __fadd_rn(sc, u2);
            }
            float excl = __fsub_rn(sc, s3);   // exact: both multiples of 2^-8 < 2^24
            int base = trow * 2048 + tcol * 256 + lane * 4;
            float c0 = rintf(__fmul_rn(__fadd_rn(excl, s0), F(255.0 / 65536.0)));
            float c1 = rintf(__fmul_rn(__fadd_rn(excl, s1), F(255.0 / 65536.0)));
            float c2 = rintf(__fmul_rn(__fadd_rn(excl, s2), F(255.0 / 65536.0)));
            float c3 = rintf(__fmul_rn(__fadd_rn(excl, s3), F(255.0 / 65536.0)));
            lutS[base + 0] = fminf(fmaxf(c0, 0.0f), 255.0f);
            lutS[base + 1] = fminf(fmaxf(c1, 0.0f), 255.0f);
            lutS[base + 2] = fminf(fmaxf(c2, 0.0f), 255.0f);
            lutS[base + 3] = fminf(fmaxf(c3, 0.0f), 255.0f);
        }
    }
    __syncthreads();

    // ------------------- phase 3: bilinear LUT interp + lab2rgb -------------
    #pragma unroll
    for (int c = 0; c < 8; ++c) {
        int col = c * 256 + t;
        int idx = rowbase + col;
        int l8 = (int)((l8p[c >> 2] >> ((c & 3) * 8)) & 0xFFu);
        float fxc = fminf(fmaxf(((float)col + 0.5f) * (1.0f / 256.0f) - 0.5f, 0.0f), 7.0f);
        int x0 = (int)floorf(fxc);
        int x1 = min(x0 + 1, 7);
        float wx = __fsub_rn(fxc, (float)x0);
        float omwx = __fsub_rn(1.0f, wx);
        float g00 = lutS[x0 * 256 + l8];
        float g01 = lutS[x1 * 256 + l8];
        float g10 = lutS[2048 + x0 * 256 + l8];
        float g11 = lutS[2048 + x1 * 256 + l8];
        float top = __fadd_rn(__fmul_rn(omwx, g00), __fmul_rn(wx, g01));
        float bot = __fadd_rn(__fmul_rn(omwx, g10), __fmul_rn(wx, g11));
        float Leq = __fmul_rn(__fadd_rn(__fmul_rn(omwy, top), __fmul_rn(wy, bot)),
                              F(100.0 / 255.0));
        lab2rgb_store(Leq, A[c], B[c], out, idx);
    }
}

// ===========================================================================
// FALLBACK: the verified 3-kernel pipeline (used only if co-residency of the
// fused kernel cannot be guaranteed on this runtime).
// ===========================================================================
__global__ __launch_bounds__(256) void k_hist(const float* __restrict__ x,
        unsigned int* __restrict__ hist,
        float2* __restrict__ ab_out,
        unsigned char* __restrict__ l8_out, int store) {
    __shared__ unsigned int h[2048];
    const int t = threadIdx.x;
    const int y = blockIdx.x;
    #pragma unroll
    for (int i = 0; i < 8; ++i) h[i * 256 + t] = 0;
    __syncthreads();
    const int rowbase = y * WIDTH;
    #pragma unroll
    for (int c = 0; c < 8; ++c) {
        int col = c * 256 + t;
        int idx = rowbase + col;
        float r = x[idx], g = x[idx + HW], b = x[idx + 2 * HW];
        int l8; float A_, B_;
        rgb2lab_px(r, g, b, l8, A_, B_);
        if (store) {
            ab_out[idx] = make_float2(A_, B_);
            l8_out[idx] = (unsigned char)l8;
        }
        atomicAdd(&h[((col >> 8) << 8) + l8], 1u);
    }
    __syncthreads();
    const int tilerow = y >> 8;
    unsigned int* gh = hist + tilerow * 2048;
    #pragma unroll
    for (int i = 0; i < 8; ++i) {
        unsigned int v = h[i * 256 + t];
        if (v) atomicAdd(&gh[i * 256 + t], v);
    }
}

__global__ __launch_bounds__(256) void k_lut(const unsigned int* __restrict__ hist,
                                             float* __restrict__ lut) {
    __shared__ float sh[256];
    __shared__ float hc[256];
    const int t = threadIdx.x;
    const int tile = blockIdx.x;
    float h = (float)hist[tile * 256 + t];
    sh[t] = fmaxf(h - 2560.0f, 0.0f);
    __syncthreads();
    for (int s = 128; s > 0; s >>= 1) {
        if (t < s) sh[t] += sh[t + s];
        __syncthreads();
    }
    float excess = sh[0];
    hc[t] = __fadd_rn(fminf(h, 2560.0f), __fmul_rn(excess, F(1.0 / 256.0)));
    __syncthreads();
    if (t == 0) {
        float c = 0.0f;
        for (int i = 0; i < 256; ++i) { c = __fadd_rn(c, hc[i]); hc[i] = c; }
    }
    __syncthreads();
    float v = rintf(__fmul_rn(hc[t], F(255.0 / 65536.0)));
    lut[tile * 256 + t] = fminf(fmaxf(v, 0.0f), 255.0f);
}

__global__ __launch_bounds__(256) void k_apply(const float* __restrict__ x,
        const float* __restrict__ lut,
        const float2* __restrict__ ab_in,
        const unsigned char* __restrict__ l8_in,
        float* __restrict__ out, int stored) {
    __shared__ float lutS[4096];
    const int t = threadIdx.x;
    const int y = blockIdx.x;

    float fyc = fminf(fmaxf(((float)y + 0.5f) * (1.0f / 256.0f) - 0.5f, 0.0f), 7.0f);
    int y0 = (int)floorf(fyc); int y1 = min(y0 + 1, 7);
    float wy = __fsub_rn(fyc, (float)y0);
    float omwy = __fsub_rn(1.0f, wy);

    const float* ltop = lut + y0 * 2048;
    const float* lbot = lut + y1 * 2048;
    #pragma unroll
    for (int i = 0; i < 8; ++i) {
        lutS[i * 256 + t]        = ltop[i * 256 + t];
        lutS[2048 + i * 256 + t] = lbot[i * 256 + t];
    }
    __syncthreads();

    const int rowbase = y * WIDTH;
    #pragma unroll
    for (int c = 0; c < 8; ++c) {
        int col = c * 256 + t;
        int idx = rowbase + col;
        int l8; float A_, B_;
        if (stored) {
            float2 ab = ab_in[idx];
            A_ = ab.x; B_ = ab.y;
            l8 = (int)l8_in[idx];
        } else {
            float r = x[idx], g = x[idx + HW], b = x[idx + 2 * HW];
            rgb2lab_px(r, g, b, l8, A_, B_);
        }
        float fxc = fminf(fmaxf(((float)col + 0.5f) * (1.0f / 256.0f) - 0.5f, 0.0f), 7.0f);
        int x0 = (int)floorf(fxc); int x1 = min(x0 + 1, 7);
        float wx = __fsub_rn(fxc, (float)x0);
        float omwx = __fsub_rn(1.0f, wx);
        float g00 = lutS[x0 * 256 + l8];
        float g01 = lutS[x1 * 256 + l8];
        float g10 = lutS[2048 + x0 * 256 + l8];
        float g11 = lutS[2048 + x1 * 256 + l8];
        float top = __fadd_rn(__fmul_rn(omwx, g00), __fmul_rn(wx, g01));
        float bot = __fadd_rn(__fmul_rn(omwx, g10), __fmul_rn(wx, g11));
        float Leq = __fmul_rn(__fadd_rn(__fmul_rn(omwy, top), __fmul_rn(wy, bot)),
                              F(100.0 / 255.0));
        lab2rgb_store(Leq, A_, B_, out, idx);
    }
}

extern "C" void kernel_launch(void* const* d_in, const int* in_sizes, int n_in,
                              void* d_out, int out_size, void* d_ws, size_t ws_size,
                              hipStream_t stream) {
    const float* x = (const float*)d_in[0];
    float* out = (float*)d_out;
    char* ws = (char*)d_ws;
    unsigned int* hist = (unsigned int*)ws;            // 64*256*4 = 64 KiB
    unsigned int* bar  = (unsigned int*)(ws + 65536);  // barrier state (8 B), zeroed below
    float* lut = (float*)(ws + 65536);                 // fallback-only; overwritten by k_lut

    // One-time host-side co-residency check for the fused kernel:
    // need 8 blocks/CU * 256 CUs >= 2048 blocks simultaneously resident.
    static int fused_ok = -1;
    if (fused_ok < 0) {
        int nb = 0, ncu = 0, dev = 0;
        (void)hipGetDevice(&dev);
        hipError_t e1 = hipOccupancyMaxActiveBlocksPerMultiprocessor(&nb, k_fused_row, 256, 0);
        hipError_t e2 = hipDeviceGetAttribute(&ncu, hipDeviceAttributeMultiprocessorCount, dev);
        fused_ok = (e1 == hipSuccess && e2 == hipSuccess && nb * ncu >= NBLK) ? 1 : 0;
    }

    // zero hist (64 KiB) + barrier state (first 64 B of the lut region)
    (void)hipMemsetAsync(ws, 0, 65536 + 64, stream);

    if (fused_ok == 1) {
        k_fused_row<<<NBLK, 256, 0, stream>>>(x, hist, bar, out);
    } else {
        const size_t off = 131072;
        float2* ab_buf = (float2*)(ws + off);                               // 32 MiB
        unsigned char* l8_buf = (unsigned char*)(ws + off + (size_t)HW * 8); // 4 MiB
        const size_t need = off + (size_t)HW * 9;
        const int store = (ws_size >= need) ? 1 : 0;
        k_hist<<<2048, 256, 0, stream>>>(x, hist, ab_buf, l8_buf, store);
        k_lut<<<64, 256, 0, stream>>>(hist, lut);
        k_apply<<<2048, 256, 0, stream>>>(x, lut, ab_buf, l8_buf, out, store);
    }
}